// Round 11
// baseline (1151.487 us; speedup 1.0000x reference)
//
#include <hip/hip_runtime.h>
#include <stdint.h>

#define N_NODES 50000
#define D 128
#define NE 800000
#define NREP 8

typedef __bf16 bf16x8 __attribute__((ext_vector_type(8)));
typedef float floatx4 __attribute__((ext_vector_type(4)));

__device__ __forceinline__ unsigned short f2bf(float f) {
    unsigned u = __float_as_uint(f);
    u += 0x7fffu + ((u >> 16) & 1u);
    return (unsigned short)(u >> 16);
}
__device__ __forceinline__ float bf2f(unsigned short h) {
    return __uint_as_float(((unsigned)h) << 16);
}
__device__ __forceinline__ void dma_lds_16(const unsigned short* g, unsigned short* l) {
    // each lane copies 16B: global g+lane*8 elems -> LDS l+lane*8 elems (contiguous 1KB/wave)
    int lane = threadIdx.x & 63;
    __builtin_amdgcn_global_load_lds(
        (const __attribute__((address_space(1))) void*)(g + lane * 8),
        (__attribute__((address_space(3))) void*)(l + lane * 8), 16, 0, 0);
}

// ---------------- fused prep: conv_xh | conv_w | hist (independent work, one dispatch) ----
// hist uses 8 counter replicas keyed by blockIdx%8: blocks round-robin across XCDs, so each
// replica's lines stay in one XCD's L2 -> no cross-XCD atomic line bouncing.
#define NB_CONV 25000   // 4*N_NODES*(D/4)/256
#define NB_W     1536   // ceil(2*196608/256)
#define NB_HIST  6250   // ceil(2*NE/256)
__global__ void k_prep(const float* __restrict__ xu, const float* __restrict__ hu,
                       const float* __restrict__ xn, const float* __restrict__ hn,
                       unsigned short* u3_u, unsigned short* u3_n,
                       const float* __restrict__ Wl, const float* __restrict__ Wr,
                       unsigned short* wt,
                       const int* __restrict__ dun, const int* __restrict__ dnu,
                       int* deg_n, int* deg_u) {
    int b = blockIdx.x;
    if (b < NB_CONV) {
        // ---- conv x/h fp32 -> bf16 into u3; layout [agg_x|agg_h|x|h] ----
        int id = b * 256 + threadIdx.x;
        const int PER = N_NODES * (D / 4);  // 1,600,000
        int arr = id / PER;
        int rem = id - arr * PER;
        int row = rem >> 5;
        int c4 = rem & 31;
        const float* src;
        unsigned short* dst;
        int colbase;
        if (arr == 0)      { src = xu; dst = u3_u; colbase = 256; }
        else if (arr == 1) { src = hu; dst = u3_u; colbase = 384; }
        else if (arr == 2) { src = xn; dst = u3_n; colbase = 256; }
        else               { src = hn; dst = u3_n; colbase = 384; }
        float4 v = *(const float4*)(src + row * D + c4 * 4);
        ushort4 o;
        o.x = f2bf(v.x); o.y = f2bf(v.y); o.z = f2bf(v.z); o.w = f2bf(v.w);
        *(ushort4*)(dst + row * 512 + colbase + c4 * 4) = o;
    } else if (b < NB_CONV + NB_W) {
        // ---- weights -> transposed stacked bf16, layout [n][k] ----
        int f = (b - NB_CONV) * 256 + threadIdx.x;
        if (f >= 2 * 196608) return;
        int t = f / 196608;
        int o = f - t * 196608;
        int n, k, g;
        const float* W;
        if (o < 131072) {  // z (g0=0) or r (g0=2), K=512
            int g0 = (o < 65536) ? 0 : 2;
            int oo = o & 65535;
            n = oo >> 9; k = oo & 511;
            int seg = k >> 7;
            W = (seg < 2) ? Wl : Wr;
            g = g0 + (seg & 1);
        } else {  // c (g=4) or h (g=5), K=256
            int oo = o - 131072;
            g = (oo < 32768) ? 4 : 5;
            oo &= 32767;
            n = oo >> 8; k = oo & 255;
            int seg = k >> 7;
            W = seg ? Wr : Wl;
        }
        int kk = k & 127;
        wt[f] = f2bf(W[((g * 2 + t) * 128 + kk) * 128 + n]);
    } else {
        // ---- degree histogram into replica (hist-block % 8) ----
        int hb = b - NB_CONV - NB_W;
        int r = hb & 7;
        int id = hb * 256 + threadIdx.x;
        if (id < NE) atomicAdd(&deg_n[r * N_NODES + dun[id]], 1);
        else if (id < 2 * NE) atomicAdd(&deg_u[r * N_NODES + dnu[id - NE]], 1);
    }
}

// scan: sum 8 replicas -> offs; also emit per-replica exclusive sub-offsets roffs[r][node]
__global__ void k_scan(const int* __restrict__ deg_n, const int* __restrict__ deg_u,
                       int* offs_n, int* offs_u, int* roffs_n, int* roffs_u) {
    const int* deg = blockIdx.x ? deg_u : deg_n;
    int* offs = blockIdx.x ? offs_u : offs_n;
    int* roffs = blockIdx.x ? roffs_u : roffs_n;
    __shared__ int lds[1024];
    int t = threadIdx.x;
    const int CH = (N_NODES + 1023) / 1024;  // 49
    int base = t * CH;
    int end = min(base + CH, N_NODES);
    int s = 0;
    for (int i = base; i < end; ++i) {
#pragma unroll
        for (int r = 0; r < NREP; ++r) s += deg[r * N_NODES + i];
    }
    lds[t] = s;
    __syncthreads();
    for (int off = 1; off < 1024; off <<= 1) {
        int v = lds[t];
        int w = (t >= off) ? lds[t - off] : 0;
        __syncthreads();
        lds[t] = v + w;
        __syncthreads();
    }
    int run = lds[t] - s;  // exclusive base
    for (int i = base; i < end; ++i) {
        offs[i] = run;
        int acc = run;
#pragma unroll
        for (int r = 0; r < NREP; ++r) {
            roffs[r * N_NODES + i] = acc;
            acc += deg[r * N_NODES + i];
        }
        run = acc;
    }
    if (t == 1023) offs[N_NODES] = lds[1023];
}

__global__ void k_scatter(const int* __restrict__ sun, const int* __restrict__ dun,
                          const int* __restrict__ snu, const int* __restrict__ dnu,
                          const int* __restrict__ roffs_n, const int* __restrict__ roffs_u,
                          int* cur_n, int* cur_u, int* srcs_n, int* srcs_u) {
    int r = blockIdx.x & 7;
    int id = blockIdx.x * blockDim.x + threadIdx.x;
    if (id < NE) {
        int d = dun[id];
        int p = roffs_n[r * N_NODES + d] + atomicAdd(&cur_n[r * N_NODES + d], 1);
        srcs_n[p] = sun[id];
    } else if (id < 2 * NE) {
        int e = id - NE;
        int d = dnu[e];
        int p = roffs_u[r * N_NODES + d] + atomicAdd(&cur_u[r * N_NODES + d], 1);
        srcs_u[p] = snu[e];
    }
}

// ------------- agg2: mean of x,h rows; 2 edge-slots/wave, 16B/lane contiguous 512B/edge ----
__global__ void k_agg2(const int* __restrict__ offs_n, const int* __restrict__ srcs_n,
                       const int* __restrict__ offs_u, const int* __restrict__ srcs_u,
                       const unsigned short* __restrict__ u3_n_ro,
                       const unsigned short* __restrict__ u3_u_ro,
                       unsigned short* u3_n, unsigned short* u3_u) {
    int dir = blockIdx.y;
    int node = blockIdx.x * 4 + (threadIdx.x >> 6);
    int lane = threadIdx.x & 63;
    const int* offs = dir ? offs_u : offs_n;
    const int* srcs = dir ? srcs_u : srcs_n;
    const unsigned short* src_feat = dir ? u3_n_ro : u3_u_ro;
    unsigned short* dst = dir ? u3_u : u3_n;
    int c0 = offs[node], c1 = offs[node + 1];
    int eslot = lane >> 5;   // which edge within a pair
    int sub = lane & 31;     // 16B chunk of the 512B [x|h] run
    int srcoff = 256 + sub * 8;
    float a[8];
#pragma unroll
    for (int i = 0; i < 8; ++i) a[i] = 0.f;
    auto acc8 = [&](uint4 v) {
        a[0] += bf2f(v.x & 0xffff); a[1] += bf2f(v.x >> 16);
        a[2] += bf2f(v.y & 0xffff); a[3] += bf2f(v.y >> 16);
        a[4] += bf2f(v.z & 0xffff); a[5] += bf2f(v.z >> 16);
        a[6] += bf2f(v.w & 0xffff); a[7] += bf2f(v.w >> 16);
    };
    int e = c0 + eslot;
    for (; e + 6 < c1; e += 8) {
        int s0 = srcs[e], s1 = srcs[e + 2], s2 = srcs[e + 4], s3 = srcs[e + 6];
        uint4 v0 = *(const uint4*)(src_feat + (size_t)s0 * 512 + srcoff);
        uint4 v1 = *(const uint4*)(src_feat + (size_t)s1 * 512 + srcoff);
        uint4 v2 = *(const uint4*)(src_feat + (size_t)s2 * 512 + srcoff);
        uint4 v3 = *(const uint4*)(src_feat + (size_t)s3 * 512 + srcoff);
        acc8(v0); acc8(v1); acc8(v2); acc8(v3);
    }
    for (; e < c1; e += 2) {
        uint4 v = *(const uint4*)(src_feat + (size_t)srcs[e] * 512 + srcoff);
        acc8(v);
    }
#pragma unroll
    for (int i = 0; i < 8; ++i) a[i] += __shfl_xor(a[i], 32);
    if (eslot == 0) {
        float inv = 1.f / (float)max(c1 - c0, 1);
        uint4 o;
        o.x = (unsigned)f2bf(a[0] * inv) | ((unsigned)f2bf(a[1] * inv) << 16);
        o.y = (unsigned)f2bf(a[2] * inv) | ((unsigned)f2bf(a[3] * inv) << 16);
        o.z = (unsigned)f2bf(a[4] * inv) | ((unsigned)f2bf(a[5] * inv) << 16);
        o.w = (unsigned)f2bf(a[6] * inv) | ((unsigned)f2bf(a[7] * inv) << 16);
        *(uint4*)(dst + (size_t)node * 512 + sub * 8) = o;
    }
}

// ------------- phase 3: z, r, cx via MFMA; verbatim R1 structure (measured 104us, VGPR 44) ----
#define GSTRIDE 520
__global__ __launch_bounds__(512, 4) void k_gates(
    const unsigned short* __restrict__ u3_n, const unsigned short* __restrict__ u3_u,
    const unsigned short* __restrict__ wt, const float* __restrict__ bias,
    unsigned short* z_n, unsigned short* z_u,
    unsigned short* cx_n, unsigned short* cx_u,
    unsigned short* u2s_n, unsigned short* u2s_u) {
    extern __shared__ unsigned short lds[];
    int t = blockIdx.y;  // 0 news, 1 user
    const unsigned short* u3 = t ? u3_u : u3_n;
    unsigned short* zb = t ? z_u : z_n;
    unsigned short* cb = t ? cx_u : cx_n;
    unsigned short* u2s = t ? u2s_u : u2s_n;
    const unsigned short* wbase = wt + t * 196608;
    const unsigned short* wz = wbase;
    const unsigned short* wr_ = wbase + 65536;
    const unsigned short* wc = wbase + 131072;

    int row0 = blockIdx.x * 64;
    int tid = threadIdx.x;
    int lane = tid & 63;
    int w = tid >> 6;           // 0..7
    int l15 = lane & 15;
    int quad = lane >> 4;
    int colg = w * 16 + l15;    // 16 cols per wave

    // stage A: wave w DMAs rows w*8 .. w*8+7 (1KB each)
#pragma unroll
    for (int i = 0; i < 8; ++i) {
        int rl = w * 8 + i;
        int r = min(row0 + rl, N_NODES - 1);
        dma_lds_16(u3 + (size_t)r * 512, lds + rl * GSTRIDE);
    }
    __syncthreads();

    floatx4 zero = {0.f, 0.f, 0.f, 0.f};
    floatx4 accz[4], accr[4], accc[4];
#pragma unroll
    for (int i = 0; i < 4; ++i) { accz[i] = zero; accr[i] = zero; accc[i] = zero; }

#pragma unroll
    for (int kt = 0; kt < 16; ++kt) {
        int ko = kt * 32 + quad * 8;
        bf16x8 a[4];
#pragma unroll
        for (int rt = 0; rt < 4; ++rt)
            a[rt] = *(const bf16x8*)(lds + (rt * 16 + l15) * GSTRIDE + ko);
        bf16x8 bz = *(const bf16x8*)(wz + colg * 512 + ko);
#pragma unroll
        for (int rt = 0; rt < 4; ++rt)
            accz[rt] = __builtin_amdgcn_mfma_f32_16x16x32_bf16(a[rt], bz, accz[rt], 0, 0, 0);
        bf16x8 br = *(const bf16x8*)(wr_ + colg * 512 + ko);
#pragma unroll
        for (int rt = 0; rt < 4; ++rt)
            accr[rt] = __builtin_amdgcn_mfma_f32_16x16x32_bf16(a[rt], br, accr[rt], 0, 0, 0);
        // c-gate: A k-ranges [agg_x: kt 0..3] and [x: kt 8..11]
        if (kt < 4 || (kt >= 8 && kt < 12)) {
            int kc = (kt < 4) ? kt : (kt - 4);
            bf16x8 bc = *(const bf16x8*)(wc + colg * 256 + kc * 32 + quad * 8);
#pragma unroll
            for (int rt = 0; rt < 4; ++rt)
                accc[rt] = __builtin_amdgcn_mfma_f32_16x16x32_bf16(a[rt], bc, accc[rt], 0, 0, 0);
        }
    }

    {
        float bz_ = bias[(0 * 2 + t) * 128 + colg] + bias[(1 * 2 + t) * 128 + colg];
        float br_ = bias[(2 * 2 + t) * 128 + colg] + bias[(3 * 2 + t) * 128 + colg];
        float bc_ = bias[(4 * 2 + t) * 128 + colg];
#pragma unroll
        for (int rt = 0; rt < 4; ++rt) {
#pragma unroll
            for (int v = 0; v < 4; ++v) {
                int rl = rt * 16 + quad * 4 + v;
                int row = row0 + rl;
                if (row < N_NODES) {
                    float zv = 1.f / (1.f + __expf(-(accz[rt][v] + bz_)));
                    float rv = 1.f / (1.f + __expf(-(accr[rt][v] + br_)));
                    float cv = accc[rt][v] + bc_;
                    float hv = bf2f(lds[rl * GSTRIDE + 384 + colg]);  // h staged in LDS
                    zb[(size_t)row * 128 + colg] = f2bf(zv);
                    cb[(size_t)row * 128 + colg] = f2bf(cv);
                    u2s[(size_t)row * 128 + colg] = f2bf(hv * rv);
                }
            }
        }
    }
}

// ------------- fused gather+out: agg_s->LDS, ht = tanh(cx + [agg_s|s]@Wh + b5) -------------
// LDS: 64 rows x 264 ushorts: [agg_s (0..127) | s (128..255) | pad 8] = 33.8KB
#define OSTRIDE 264
__global__ __launch_bounds__(512, 4) void k_out(
    const unsigned short* __restrict__ u2s_n, const unsigned short* __restrict__ u2s_u,
    const unsigned short* __restrict__ u3_n, const unsigned short* __restrict__ u3_u,
    const int* __restrict__ offs_n, const int* __restrict__ srcs_n,
    const int* __restrict__ offs_u, const int* __restrict__ srcs_u,
    const unsigned short* __restrict__ wt, const float* __restrict__ bias,
    const unsigned short* __restrict__ z_n, const unsigned short* __restrict__ z_u,
    const unsigned short* __restrict__ cx_n, const unsigned short* __restrict__ cx_u,
    float* out) {
    extern __shared__ unsigned short lds[];
    int t = blockIdx.y;
    const unsigned short* u2own = t ? u2s_u : u2s_n;
    const unsigned short* u2src = t ? u2s_n : u2s_u;
    const unsigned short* u3 = t ? u3_u : u3_n;
    const int* offs = t ? offs_u : offs_n;
    const int* srcs = t ? srcs_u : srcs_n;
    const unsigned short* zb = t ? z_u : z_n;
    const unsigned short* cb = t ? cx_u : cx_n;
    float* op = out + (t ? 0 : (size_t)N_NODES * D);  // output order: h_user first
    const unsigned short* wh = wt + t * 196608 + 163840;

    int row0 = blockIdx.x * 64;
    int tid = threadIdx.x;
    int lane = tid & 63;
    int w = tid >> 6;
    int l15 = lane & 15;
    int quad = lane >> 4;
    int colg = w * 16 + l15;

    // ---- stage own s rows w*8..w*8+7 into LDS cols 128..255 (4 rows per b128 store) ----
    {
        int q16 = lane >> 4;   // 0..3
        int s16 = lane & 15;
#pragma unroll
        for (int i = 0; i < 2; ++i) {
            int r = w * 8 + i * 4 + q16;
            int gr = min(row0 + r, N_NODES - 1);
            uint4 v = *(const uint4*)(u2own + (size_t)gr * 128 + s16 * 8);
            *(uint4*)(lds + r * OSTRIDE + 128 + s16 * 8) = v;
        }
    }

    // ---- gather mean of source s into LDS cols 0..127; 8 rows/wave, 4 edge-slots ----
    {
        int eslot = lane >> 4;
        int sub = lane & 15;
        for (int i = 0; i < 8; ++i) {
            int rl = w * 8 + i;
            int node = min(row0 + rl, N_NODES - 1);
            int c0 = offs[node], c1 = offs[node + 1];
            float a[8];
#pragma unroll
            for (int j = 0; j < 8; ++j) a[j] = 0.f;
            auto acc8 = [&](uint4 v) {
                a[0] += bf2f(v.x & 0xffff); a[1] += bf2f(v.x >> 16);
                a[2] += bf2f(v.y & 0xffff); a[3] += bf2f(v.y >> 16);
                a[4] += bf2f(v.z & 0xffff); a[5] += bf2f(v.z >> 16);
                a[6] += bf2f(v.w & 0xffff); a[7] += bf2f(v.w >> 16);
            };
            int e = c0 + eslot;
            for (; e + 12 < c1; e += 16) {
                int s0 = srcs[e], s1 = srcs[e + 4], s2 = srcs[e + 8], s3 = srcs[e + 12];
                uint4 v0 = *(const uint4*)(u2src + (size_t)s0 * 128 + sub * 8);
                uint4 v1 = *(const uint4*)(u2src + (size_t)s1 * 128 + sub * 8);
                uint4 v2 = *(const uint4*)(u2src + (size_t)s2 * 128 + sub * 8);
                uint4 v3 = *(const uint4*)(u2src + (size_t)s3 * 128 + sub * 8);
                acc8(v0); acc8(v1); acc8(v2); acc8(v3);
            }
            for (; e < c1; e += 4) {
                uint4 v = *(const uint4*)(u2src + (size_t)srcs[e] * 128 + sub * 8);
                acc8(v);
            }
#pragma unroll
            for (int j = 0; j < 8; ++j) a[j] += __shfl_xor(a[j], 32);
#pragma unroll
            for (int j = 0; j < 8; ++j) a[j] += __shfl_xor(a[j], 16);
            if (eslot == 0) {
                float inv = 1.f / (float)max(c1 - c0, 1);
                uint4 o;
                o.x = (unsigned)f2bf(a[0] * inv) | ((unsigned)f2bf(a[1] * inv) << 16);
                o.y = (unsigned)f2bf(a[2] * inv) | ((unsigned)f2bf(a[3] * inv) << 16);
                o.z = (unsigned)f2bf(a[4] * inv) | ((unsigned)f2bf(a[5] * inv) << 16);
                o.w = (unsigned)f2bf(a[6] * inv) | ((unsigned)f2bf(a[7] * inv) << 16);
                *(uint4*)(lds + rl * OSTRIDE + sub * 8) = o;
            }
        }
    }
    __syncthreads();

    floatx4 zero = {0.f, 0.f, 0.f, 0.f};
    floatx4 acc[4];
#pragma unroll
    for (int i = 0; i < 4; ++i) acc[i] = zero;

    const unsigned short* ph = wh + (size_t)colg * 256 + quad * 8;
#pragma unroll
    for (int kt = 0; kt < 8; ++kt) {
        int ko = kt * 32 + quad * 8;
        bf16x8 b = *(const bf16x8*)(ph + kt * 32);
        bf16x8 a[4];
#pragma unroll
        for (int rt = 0; rt < 4; ++rt)
            a[rt] = *(const bf16x8*)(lds + (rt * 16 + l15) * OSTRIDE + ko);
#pragma unroll
        for (int rt = 0; rt < 4; ++rt)
            acc[rt] = __builtin_amdgcn_mfma_f32_16x16x32_bf16(a[rt], b, acc[rt], 0, 0, 0);
    }

    {
        float bh_ = bias[(5 * 2 + t) * 128 + colg];
#pragma unroll
        for (int rt = 0; rt < 4; ++rt) {
#pragma unroll
            for (int v = 0; v < 4; ++v) {
                int row = row0 + rt * 16 + quad * 4 + v;
                if (row < N_NODES) {
                    float x = bf2f(cb[(size_t)row * 128 + colg]) + acc[rt][v] + bh_;
                    x = fminf(fmaxf(x, -15.f), 15.f);
                    float e = __expf(2.f * x);
                    float ht = (e - 1.f) / (e + 1.f);
                    float zv = bf2f(zb[(size_t)row * 128 + colg]);
                    float hv = bf2f(u3[(size_t)row * 512 + 384 + colg]);
                    op[(size_t)row * 128 + colg] = zv * hv + (1.f - zv) * ht;
                }
            }
        }
    }
}

extern "C" void kernel_launch(void* const* d_in, const int* in_sizes, int n_in,
                              void* d_out, int out_size, void* d_ws, size_t ws_size,
                              hipStream_t stream) {
    const float* xu = (const float*)d_in[0];
    const float* xn = (const float*)d_in[1];
    const float* hu = (const float*)d_in[2];
    const float* hn = (const float*)d_in[3];
    const float* Wl = (const float*)d_in[4];
    const float* Wr = (const float*)d_in[5];
    const float* b  = (const float*)d_in[6];
    const int* sun = (const int*)d_in[7];
    const int* dun = (const int*)d_in[8];
    const int* snu = (const int*)d_in[9];
    const int* dnu = (const int*)d_in[10];
    float* out = (float*)d_out;

    char* ws = (char*)d_ws;
    size_t off = 0;
    auto alloc = [&](size_t bytes) -> void* {
        void* p = ws + off;
        off += (bytes + 255) & ~(size_t)255;
        return p;
    };
    unsigned short* wt = (unsigned short*)alloc((size_t)2 * 196608 * 2);
    // zeros region: deg_n[8N] deg_u[8N] cur_n[8N] cur_u[8N]
    int* zeros = (int*)alloc((size_t)4 * NREP * N_NODES * 4);
    int* deg_n = zeros;
    int* deg_u = zeros + NREP * N_NODES;
    int* cur_n = zeros + 2 * NREP * N_NODES;
    int* cur_u = zeros + 3 * NREP * N_NODES;
    int* offs_n = (int*)alloc((size_t)(N_NODES + 1) * 4);
    int* offs_u = (int*)alloc((size_t)(N_NODES + 1) * 4);
    int* roffs_n = (int*)alloc((size_t)NREP * N_NODES * 4);
    int* roffs_u = (int*)alloc((size_t)NREP * N_NODES * 4);
    int* srcs_n = (int*)alloc((size_t)NE * 4);
    int* srcs_u = (int*)alloc((size_t)NE * 4);
    unsigned short* u3_n = (unsigned short*)alloc((size_t)N_NODES * 512 * 2);
    unsigned short* u3_u = (unsigned short*)alloc((size_t)N_NODES * 512 * 2);
    unsigned short* u2s_n = (unsigned short*)alloc((size_t)N_NODES * 128 * 2);
    unsigned short* u2s_u = (unsigned short*)alloc((size_t)N_NODES * 128 * 2);
    unsigned short* z_n  = (unsigned short*)alloc((size_t)N_NODES * 128 * 2);
    unsigned short* z_u  = (unsigned short*)alloc((size_t)N_NODES * 128 * 2);
    unsigned short* cx_n = (unsigned short*)alloc((size_t)N_NODES * 128 * 2);
    unsigned short* cx_u = (unsigned short*)alloc((size_t)N_NODES * 128 * 2);
    (void)in_sizes; (void)n_in; (void)out_size; (void)ws_size;

    (void)hipMemsetAsync(zeros, 0, (size_t)4 * NREP * N_NODES * 4, stream);
    k_prep<<<NB_CONV + NB_W + NB_HIST, 256, 0, stream>>>(
        xu, hu, xn, hn, u3_u, u3_n, Wl, Wr, wt, dun, dnu, deg_n, deg_u);
    k_scan<<<2, 1024, 0, stream>>>(deg_n, deg_u, offs_n, offs_u, roffs_n, roffs_u);
    k_scatter<<<(2 * NE + 255) / 256, 256, 0, stream>>>(sun, dun, snu, dnu, roffs_n, roffs_u,
                                                        cur_n, cur_u, srcs_n, srcs_u);
    k_agg2<<<dim3(N_NODES / 4, 2), 256, 0, stream>>>(offs_n, srcs_n, offs_u, srcs_u,
                                                     u3_n, u3_u, u3_n, u3_u);
    k_gates<<<dim3((N_NODES + 63) / 64, 2), 512, 64 * GSTRIDE * 2, stream>>>(
        u3_n, u3_u, wt, b, z_n, z_u, cx_n, cx_u, u2s_n, u2s_u);
    k_out<<<dim3((N_NODES + 63) / 64, 2), 512, 64 * OSTRIDE * 2, stream>>>(
        u2s_n, u2s_u, u3_n, u3_u, offs_n, srcs_n, offs_u, srcs_u, wt, b,
        z_n, z_u, cx_n, cx_u, out);
}

// Round 12
// 590.062 us; speedup vs baseline: 1.9515x; 1.9515x over previous
//
#include <hip/hip_runtime.h>
#include <stdint.h>

#define N_NODES 50000
#define D 128
#define NE 800000
#define NREP 8
#define SCH 512
#define NSB ((N_NODES + SCH - 1) / SCH)   // 98

typedef __bf16 bf16x8 __attribute__((ext_vector_type(8)));
typedef float floatx4 __attribute__((ext_vector_type(4)));

__device__ __forceinline__ unsigned short f2bf(float f) {
    unsigned u = __float_as_uint(f);
    u += 0x7fffu + ((u >> 16) & 1u);
    return (unsigned short)(u >> 16);
}
__device__ __forceinline__ float bf2f(unsigned short h) {
    return __uint_as_float(((unsigned)h) << 16);
}
__device__ __forceinline__ void dma_lds_16(const unsigned short* g, unsigned short* l) {
    // each lane copies 16B: global g+lane*8 elems -> LDS l+lane*8 elems (contiguous 1KB/wave)
    int lane = threadIdx.x & 63;
    __builtin_amdgcn_global_load_lds(
        (const __attribute__((address_space(1))) void*)(g + lane * 8),
        (__attribute__((address_space(3))) void*)(l + lane * 8), 16, 0, 0);
}

// ---------------- fused prep: conv_xh | conv_w | hist (independent work, one dispatch) ----
// hist uses 8 counter replicas keyed by blockIdx%8: blocks round-robin across XCDs, so each
// replica's lines stay in one XCD's L2 -> no cross-XCD atomic line bouncing.
#define NB_CONV 25000   // 4*N_NODES*(D/4)/256
#define NB_W     1536   // ceil(2*196608/256)
#define NB_HIST  6250   // ceil(2*NE/256)
__global__ void k_prep(const float* __restrict__ xu, const float* __restrict__ hu,
                       const float* __restrict__ xn, const float* __restrict__ hn,
                       unsigned short* u3_u, unsigned short* u3_n,
                       const float* __restrict__ Wl, const float* __restrict__ Wr,
                       unsigned short* wt,
                       const int* __restrict__ dun, const int* __restrict__ dnu,
                       int* deg_n, int* deg_u) {
    int b = blockIdx.x;
    if (b < NB_CONV) {
        // ---- conv x/h fp32 -> bf16 into u3; layout [agg_x|agg_h|x|h] ----
        int id = b * 256 + threadIdx.x;
        const int PER = N_NODES * (D / 4);  // 1,600,000
        int arr = id / PER;
        int rem = id - arr * PER;
        int row = rem >> 5;
        int c4 = rem & 31;
        const float* src;
        unsigned short* dst;
        int colbase;
        if (arr == 0)      { src = xu; dst = u3_u; colbase = 256; }
        else if (arr == 1) { src = hu; dst = u3_u; colbase = 384; }
        else if (arr == 2) { src = xn; dst = u3_n; colbase = 256; }
        else               { src = hn; dst = u3_n; colbase = 384; }
        float4 v = *(const float4*)(src + row * D + c4 * 4);
        ushort4 o;
        o.x = f2bf(v.x); o.y = f2bf(v.y); o.z = f2bf(v.z); o.w = f2bf(v.w);
        *(ushort4*)(dst + row * 512 + colbase + c4 * 4) = o;
    } else if (b < NB_CONV + NB_W) {
        // ---- weights -> transposed stacked bf16, layout [n][k] ----
        int f = (b - NB_CONV) * 256 + threadIdx.x;
        if (f >= 2 * 196608) return;
        int t = f / 196608;
        int o = f - t * 196608;
        int n, k, g;
        const float* W;
        if (o < 131072) {  // z (g0=0) or r (g0=2), K=512
            int g0 = (o < 65536) ? 0 : 2;
            int oo = o & 65535;
            n = oo >> 9; k = oo & 511;
            int seg = k >> 7;
            W = (seg < 2) ? Wl : Wr;
            g = g0 + (seg & 1);
        } else {  // c (g=4) or h (g=5), K=256
            int oo = o - 131072;
            g = (oo < 32768) ? 4 : 5;
            oo &= 32767;
            n = oo >> 8; k = oo & 255;
            int seg = k >> 7;
            W = seg ? Wr : Wl;
        }
        int kk = k & 127;
        wt[f] = f2bf(W[((g * 2 + t) * 128 + kk) * 128 + n]);
    } else {
        // ---- degree histogram into replica (hist-block % 8) ----
        int hb = b - NB_CONV - NB_W;
        int r = hb & 7;
        int id = hb * 256 + threadIdx.x;
        if (id < NE) atomicAdd(&deg_n[r * N_NODES + dun[id]], 1);
        else if (id < 2 * NE) atomicAdd(&deg_u[r * N_NODES + dnu[id - NE]], 1);
    }
}

// ---- scan phase A: block (b,dir) sums its 512-node chunk over 8 replicas -> part ----
__global__ void k_scan_a(const int* __restrict__ deg_n, const int* __restrict__ deg_u,
                         int* part) {
    int dir = blockIdx.y;
    const int* deg = dir ? deg_u : deg_n;
    int t = threadIdx.x;
    int node = blockIdx.x * SCH + t;
    int s = 0;
    if (node < N_NODES) {
#pragma unroll
        for (int r = 0; r < NREP; ++r) s += deg[r * N_NODES + node];  // coalesced per r
    }
    __shared__ int lds[SCH];
    lds[t] = s;
    __syncthreads();
    for (int off = SCH / 2; off > 0; off >>= 1) {
        if (t < off) lds[t] += lds[t + off];
        __syncthreads();
    }
    if (t == 0) part[dir * NSB + blockIdx.x] = lds[0];
}

// ---- scan phase B: base from partials, in-block prefix, emit offs + roffs ----
__global__ void k_scan_b(const int* __restrict__ deg_n, const int* __restrict__ deg_u,
                         const int* __restrict__ part,
                         int* offs_n, int* offs_u, int* roffs_n, int* roffs_u) {
    int dir = blockIdx.y;
    const int* deg = dir ? deg_u : deg_n;
    int* offs = dir ? offs_u : offs_n;
    int* roffs = dir ? roffs_u : roffs_n;
    int b = blockIdx.x;
    int t = threadIdx.x;

    __shared__ int bb[128];
    if (t < 128) bb[t] = (t < b) ? part[dir * NSB + t] : 0;  // NSB=98 < 128
    __syncthreads();
    for (int off = 64; off > 0; off >>= 1) {
        if (t < off) bb[t] += bb[t + off];
        __syncthreads();
    }
    int base = bb[0];
    __syncthreads();

    int node = b * SCH + t;
    int sr[NREP];
    int nodesum = 0;
#pragma unroll
    for (int r = 0; r < NREP; ++r) {
        sr[r] = (node < N_NODES) ? deg[r * N_NODES + node] : 0;  // coalesced per r
        nodesum += sr[r];
    }
    __shared__ int lds[SCH];
    lds[t] = nodesum;
    __syncthreads();
    for (int off = 1; off < SCH; off <<= 1) {
        int v = lds[t];
        int w = (t >= off) ? lds[t - off] : 0;
        __syncthreads();
        lds[t] = v + w;
        __syncthreads();
    }
    int incl = lds[t];
    int excl = incl - nodesum;
    if (node < N_NODES) {
        int acc = base + excl;
        offs[node] = acc;
#pragma unroll
        for (int r = 0; r < NREP; ++r) {
            roffs[r * N_NODES + node] = acc;   // coalesced per r
            acc += sr[r];
        }
    }
    if (b == NSB - 1 && t == SCH - 1) offs[N_NODES] = base + incl;
}

__global__ void k_scatter(const int* __restrict__ sun, const int* __restrict__ dun,
                          const int* __restrict__ snu, const int* __restrict__ dnu,
                          const int* __restrict__ roffs_n, const int* __restrict__ roffs_u,
                          int* cur_n, int* cur_u, int* srcs_n, int* srcs_u) {
    int r = blockIdx.x & 7;
    int id = blockIdx.x * blockDim.x + threadIdx.x;
    if (id < NE) {
        int d = dun[id];
        int p = roffs_n[r * N_NODES + d] + atomicAdd(&cur_n[r * N_NODES + d], 1);
        srcs_n[p] = sun[id];
    } else if (id < 2 * NE) {
        int e = id - NE;
        int d = dnu[e];
        int p = roffs_u[r * N_NODES + d] + atomicAdd(&cur_u[r * N_NODES + d], 1);
        srcs_u[p] = snu[e];
    }
}

// ------------- agg2: mean of x,h rows; 2 edge-slots/wave, 16B/lane contiguous 512B/edge ----
__global__ void k_agg2(const int* __restrict__ offs_n, const int* __restrict__ srcs_n,
                       const int* __restrict__ offs_u, const int* __restrict__ srcs_u,
                       const unsigned short* __restrict__ u3_n_ro,
                       const unsigned short* __restrict__ u3_u_ro,
                       unsigned short* u3_n, unsigned short* u3_u) {
    int dir = blockIdx.y;
    int node = blockIdx.x * 4 + (threadIdx.x >> 6);
    int lane = threadIdx.x & 63;
    const int* offs = dir ? offs_u : offs_n;
    const int* srcs = dir ? srcs_u : srcs_n;
    const unsigned short* src_feat = dir ? u3_n_ro : u3_u_ro;
    unsigned short* dst = dir ? u3_u : u3_n;
    int c0 = offs[node], c1 = offs[node + 1];
    int eslot = lane >> 5;   // which edge within a pair
    int sub = lane & 31;     // 16B chunk of the 512B [x|h] run
    int srcoff = 256 + sub * 8;
    float a[8];
#pragma unroll
    for (int i = 0; i < 8; ++i) a[i] = 0.f;
    auto acc8 = [&](uint4 v) {
        a[0] += bf2f(v.x & 0xffff); a[1] += bf2f(v.x >> 16);
        a[2] += bf2f(v.y & 0xffff); a[3] += bf2f(v.y >> 16);
        a[4] += bf2f(v.z & 0xffff); a[5] += bf2f(v.z >> 16);
        a[6] += bf2f(v.w & 0xffff); a[7] += bf2f(v.w >> 16);
    };
    int e = c0 + eslot;
    for (; e + 6 < c1; e += 8) {
        int s0 = srcs[e], s1 = srcs[e + 2], s2 = srcs[e + 4], s3 = srcs[e + 6];
        uint4 v0 = *(const uint4*)(src_feat + (size_t)s0 * 512 + srcoff);
        uint4 v1 = *(const uint4*)(src_feat + (size_t)s1 * 512 + srcoff);
        uint4 v2 = *(const uint4*)(src_feat + (size_t)s2 * 512 + srcoff);
        uint4 v3 = *(const uint4*)(src_feat + (size_t)s3 * 512 + srcoff);
        acc8(v0); acc8(v1); acc8(v2); acc8(v3);
    }
    for (; e < c1; e += 2) {
        uint4 v = *(const uint4*)(src_feat + (size_t)srcs[e] * 512 + srcoff);
        acc8(v);
    }
#pragma unroll
    for (int i = 0; i < 8; ++i) a[i] += __shfl_xor(a[i], 32);
    if (eslot == 0) {
        float inv = 1.f / (float)max(c1 - c0, 1);
        uint4 o;
        o.x = (unsigned)f2bf(a[0] * inv) | ((unsigned)f2bf(a[1] * inv) << 16);
        o.y = (unsigned)f2bf(a[2] * inv) | ((unsigned)f2bf(a[3] * inv) << 16);
        o.z = (unsigned)f2bf(a[4] * inv) | ((unsigned)f2bf(a[5] * inv) << 16);
        o.w = (unsigned)f2bf(a[6] * inv) | ((unsigned)f2bf(a[7] * inv) << 16);
        *(uint4*)(dst + (size_t)node * 512 + sub * 8) = o;
    }
}

// ------------- phase 3: z, r, cx via MFMA; verbatim R1 structure (measured 104us, VGPR 44) ----
#define GSTRIDE 520
__global__ __launch_bounds__(512, 4) void k_gates(
    const unsigned short* __restrict__ u3_n, const unsigned short* __restrict__ u3_u,
    const unsigned short* __restrict__ wt, const float* __restrict__ bias,
    unsigned short* z_n, unsigned short* z_u,
    unsigned short* cx_n, unsigned short* cx_u,
    unsigned short* u2s_n, unsigned short* u2s_u) {
    extern __shared__ unsigned short lds[];
    int t = blockIdx.y;  // 0 news, 1 user
    const unsigned short* u3 = t ? u3_u : u3_n;
    unsigned short* zb = t ? z_u : z_n;
    unsigned short* cb = t ? cx_u : cx_n;
    unsigned short* u2s = t ? u2s_u : u2s_n;
    const unsigned short* wbase = wt + t * 196608;
    const unsigned short* wz = wbase;
    const unsigned short* wr_ = wbase + 65536;
    const unsigned short* wc = wbase + 131072;

    int row0 = blockIdx.x * 64;
    int tid = threadIdx.x;
    int lane = tid & 63;
    int w = tid >> 6;           // 0..7
    int l15 = lane & 15;
    int quad = lane >> 4;
    int colg = w * 16 + l15;    // 16 cols per wave

    // stage A: wave w DMAs rows w*8 .. w*8+7 (1KB each)
#pragma unroll
    for (int i = 0; i < 8; ++i) {
        int rl = w * 8 + i;
        int r = min(row0 + rl, N_NODES - 1);
        dma_lds_16(u3 + (size_t)r * 512, lds + rl * GSTRIDE);
    }
    __syncthreads();

    floatx4 zero = {0.f, 0.f, 0.f, 0.f};
    floatx4 accz[4], accr[4], accc[4];
#pragma unroll
    for (int i = 0; i < 4; ++i) { accz[i] = zero; accr[i] = zero; accc[i] = zero; }

#pragma unroll
    for (int kt = 0; kt < 16; ++kt) {
        int ko = kt * 32 + quad * 8;
        bf16x8 a[4];
#pragma unroll
        for (int rt = 0; rt < 4; ++rt)
            a[rt] = *(const bf16x8*)(lds + (rt * 16 + l15) * GSTRIDE + ko);
        bf16x8 bz = *(const bf16x8*)(wz + colg * 512 + ko);
#pragma unroll
        for (int rt = 0; rt < 4; ++rt)
            accz[rt] = __builtin_amdgcn_mfma_f32_16x16x32_bf16(a[rt], bz, accz[rt], 0, 0, 0);
        bf16x8 br = *(const bf16x8*)(wr_ + colg * 512 + ko);
#pragma unroll
        for (int rt = 0; rt < 4; ++rt)
            accr[rt] = __builtin_amdgcn_mfma_f32_16x16x32_bf16(a[rt], br, accr[rt], 0, 0, 0);
        // c-gate: A k-ranges [agg_x: kt 0..3] and [x: kt 8..11]
        if (kt < 4 || (kt >= 8 && kt < 12)) {
            int kc = (kt < 4) ? kt : (kt - 4);
            bf16x8 bc = *(const bf16x8*)(wc + colg * 256 + kc * 32 + quad * 8);
#pragma unroll
            for (int rt = 0; rt < 4; ++rt)
                accc[rt] = __builtin_amdgcn_mfma_f32_16x16x32_bf16(a[rt], bc, accc[rt], 0, 0, 0);
        }
    }

    {
        float bz_ = bias[(0 * 2 + t) * 128 + colg] + bias[(1 * 2 + t) * 128 + colg];
        float br_ = bias[(2 * 2 + t) * 128 + colg] + bias[(3 * 2 + t) * 128 + colg];
        float bc_ = bias[(4 * 2 + t) * 128 + colg];
#pragma unroll
        for (int rt = 0; rt < 4; ++rt) {
#pragma unroll
            for (int v = 0; v < 4; ++v) {
                int rl = rt * 16 + quad * 4 + v;
                int row = row0 + rl;
                if (row < N_NODES) {
                    float zv = 1.f / (1.f + __expf(-(accz[rt][v] + bz_)));
                    float rv = 1.f / (1.f + __expf(-(accr[rt][v] + br_)));
                    float cv = accc[rt][v] + bc_;
                    float hv = bf2f(lds[rl * GSTRIDE + 384 + colg]);  // h staged in LDS
                    zb[(size_t)row * 128 + colg] = f2bf(zv);
                    cb[(size_t)row * 128 + colg] = f2bf(cv);
                    u2s[(size_t)row * 128 + colg] = f2bf(hv * rv);
                }
            }
        }
    }
}

// ------------- fused gather+out: agg_s->LDS, ht = tanh(cx + [agg_s|s]@Wh + b5) -------------
// LDS: 64 rows x 264 ushorts: [agg_s (0..127) | s (128..255) | pad 8] = 33.8KB
#define OSTRIDE 264
__global__ __launch_bounds__(512, 4) void k_out(
    const unsigned short* __restrict__ u2s_n, const unsigned short* __restrict__ u2s_u,
    const unsigned short* __restrict__ u3_n, const unsigned short* __restrict__ u3_u,
    const int* __restrict__ offs_n, const int* __restrict__ srcs_n,
    const int* __restrict__ offs_u, const int* __restrict__ srcs_u,
    const unsigned short* __restrict__ wt, const float* __restrict__ bias,
    const unsigned short* __restrict__ z_n, const unsigned short* __restrict__ z_u,
    const unsigned short* __restrict__ cx_n, const unsigned short* __restrict__ cx_u,
    float* out) {
    extern __shared__ unsigned short lds[];
    int t = blockIdx.y;
    const unsigned short* u2own = t ? u2s_u : u2s_n;
    const unsigned short* u2src = t ? u2s_n : u2s_u;
    const unsigned short* u3 = t ? u3_u : u3_n;
    const int* offs = t ? offs_u : offs_n;
    const int* srcs = t ? srcs_u : srcs_n;
    const unsigned short* zb = t ? z_u : z_n;
    const unsigned short* cb = t ? cx_u : cx_n;
    float* op = out + (t ? 0 : (size_t)N_NODES * D);  // output order: h_user first
    const unsigned short* wh = wt + t * 196608 + 163840;

    int row0 = blockIdx.x * 64;
    int tid = threadIdx.x;
    int lane = tid & 63;
    int w = tid >> 6;
    int l15 = lane & 15;
    int quad = lane >> 4;
    int colg = w * 16 + l15;

    // ---- stage own s rows w*8..w*8+7 into LDS cols 128..255 (4 rows per b128 store) ----
    {
        int q16 = lane >> 4;   // 0..3
        int s16 = lane & 15;
#pragma unroll
        for (int i = 0; i < 2; ++i) {
            int r = w * 8 + i * 4 + q16;
            int gr = min(row0 + r, N_NODES - 1);
            uint4 v = *(const uint4*)(u2own + (size_t)gr * 128 + s16 * 8);
            *(uint4*)(lds + r * OSTRIDE + 128 + s16 * 8) = v;
        }
    }

    // ---- gather mean of source s into LDS cols 0..127; 8 rows/wave, 4 edge-slots ----
    {
        int eslot = lane >> 4;
        int sub = lane & 15;
        for (int i = 0; i < 8; ++i) {
            int rl = w * 8 + i;
            int node = min(row0 + rl, N_NODES - 1);
            int c0 = offs[node], c1 = offs[node + 1];
            float a[8];
#pragma unroll
            for (int j = 0; j < 8; ++j) a[j] = 0.f;
            auto acc8 = [&](uint4 v) {
                a[0] += bf2f(v.x & 0xffff); a[1] += bf2f(v.x >> 16);
                a[2] += bf2f(v.y & 0xffff); a[3] += bf2f(v.y >> 16);
                a[4] += bf2f(v.z & 0xffff); a[5] += bf2f(v.z >> 16);
                a[6] += bf2f(v.w & 0xffff); a[7] += bf2f(v.w >> 16);
            };
            int e = c0 + eslot;
            for (; e + 12 < c1; e += 16) {
                int s0 = srcs[e], s1 = srcs[e + 4], s2 = srcs[e + 8], s3 = srcs[e + 12];
                uint4 v0 = *(const uint4*)(u2src + (size_t)s0 * 128 + sub * 8);
                uint4 v1 = *(const uint4*)(u2src + (size_t)s1 * 128 + sub * 8);
                uint4 v2 = *(const uint4*)(u2src + (size_t)s2 * 128 + sub * 8);
                uint4 v3 = *(const uint4*)(u2src + (size_t)s3 * 128 + sub * 8);
                acc8(v0); acc8(v1); acc8(v2); acc8(v3);
            }
            for (; e < c1; e += 4) {
                uint4 v = *(const uint4*)(u2src + (size_t)srcs[e] * 128 + sub * 8);
                acc8(v);
            }
#pragma unroll
            for (int j = 0; j < 8; ++j) a[j] += __shfl_xor(a[j], 32);
#pragma unroll
            for (int j = 0; j < 8; ++j) a[j] += __shfl_xor(a[j], 16);
            if (eslot == 0) {
                float inv = 1.f / (float)max(c1 - c0, 1);
                uint4 o;
                o.x = (unsigned)f2bf(a[0] * inv) | ((unsigned)f2bf(a[1] * inv) << 16);
                o.y = (unsigned)f2bf(a[2] * inv) | ((unsigned)f2bf(a[3] * inv) << 16);
                o.z = (unsigned)f2bf(a[4] * inv) | ((unsigned)f2bf(a[5] * inv) << 16);
                o.w = (unsigned)f2bf(a[6] * inv) | ((unsigned)f2bf(a[7] * inv) << 16);
                *(uint4*)(lds + rl * OSTRIDE + sub * 8) = o;
            }
        }
    }
    __syncthreads();

    floatx4 zero = {0.f, 0.f, 0.f, 0.f};
    floatx4 acc[4];
#pragma unroll
    for (int i = 0; i < 4; ++i) acc[i] = zero;

    const unsigned short* ph = wh + (size_t)colg * 256 + quad * 8;
#pragma unroll
    for (int kt = 0; kt < 8; ++kt) {
        int ko = kt * 32 + quad * 8;
        bf16x8 b = *(const bf16x8*)(ph + kt * 32);
        bf16x8 a[4];
#pragma unroll
        for (int rt = 0; rt < 4; ++rt)
            a[rt] = *(const bf16x8*)(lds + (rt * 16 + l15) * OSTRIDE + ko);
#pragma unroll
        for (int rt = 0; rt < 4; ++rt)
            acc[rt] = __builtin_amdgcn_mfma_f32_16x16x32_bf16(a[rt], b, acc[rt], 0, 0, 0);
    }

    {
        float bh_ = bias[(5 * 2 + t) * 128 + colg];
#pragma unroll
        for (int rt = 0; rt < 4; ++rt) {
#pragma unroll
            for (int v = 0; v < 4; ++v) {
                int row = row0 + rt * 16 + quad * 4 + v;
                if (row < N_NODES) {
                    float x = bf2f(cb[(size_t)row * 128 + colg]) + acc[rt][v] + bh_;
                    x = fminf(fmaxf(x, -15.f), 15.f);
                    float e = __expf(2.f * x);
                    float ht = (e - 1.f) / (e + 1.f);
                    float zv = bf2f(zb[(size_t)row * 128 + colg]);
                    float hv = bf2f(u3[(size_t)row * 512 + 384 + colg]);
                    op[(size_t)row * 128 + colg] = zv * hv + (1.f - zv) * ht;
                }
            }
        }
    }
}

extern "C" void kernel_launch(void* const* d_in, const int* in_sizes, int n_in,
                              void* d_out, int out_size, void* d_ws, size_t ws_size,
                              hipStream_t stream) {
    const float* xu = (const float*)d_in[0];
    const float* xn = (const float*)d_in[1];
    const float* hu = (const float*)d_in[2];
    const float* hn = (const float*)d_in[3];
    const float* Wl = (const float*)d_in[4];
    const float* Wr = (const float*)d_in[5];
    const float* b  = (const float*)d_in[6];
    const int* sun = (const int*)d_in[7];
    const int* dun = (const int*)d_in[8];
    const int* snu = (const int*)d_in[9];
    const int* dnu = (const int*)d_in[10];
    float* out = (float*)d_out;

    char* ws = (char*)d_ws;
    size_t off = 0;
    auto alloc = [&](size_t bytes) -> void* {
        void* p = ws + off;
        off += (bytes + 255) & ~(size_t)255;
        return p;
    };
    unsigned short* wt = (unsigned short*)alloc((size_t)2 * 196608 * 2);
    // zeros region: deg_n[8N] deg_u[8N] cur_n[8N] cur_u[8N]
    int* zeros = (int*)alloc((size_t)4 * NREP * N_NODES * 4);
    int* deg_n = zeros;
    int* deg_u = zeros + NREP * N_NODES;
    int* cur_n = zeros + 2 * NREP * N_NODES;
    int* cur_u = zeros + 3 * NREP * N_NODES;
    int* offs_n = (int*)alloc((size_t)(N_NODES + 1) * 4);
    int* offs_u = (int*)alloc((size_t)(N_NODES + 1) * 4);
    int* roffs_n = (int*)alloc((size_t)NREP * N_NODES * 4);
    int* roffs_u = (int*)alloc((size_t)NREP * N_NODES * 4);
    int* part = (int*)alloc((size_t)2 * NSB * 4);
    int* srcs_n = (int*)alloc((size_t)NE * 4);
    int* srcs_u = (int*)alloc((size_t)NE * 4);
    unsigned short* u3_n = (unsigned short*)alloc((size_t)N_NODES * 512 * 2);
    unsigned short* u3_u = (unsigned short*)alloc((size_t)N_NODES * 512 * 2);
    unsigned short* u2s_n = (unsigned short*)alloc((size_t)N_NODES * 128 * 2);
    unsigned short* u2s_u = (unsigned short*)alloc((size_t)N_NODES * 128 * 2);
    unsigned short* z_n  = (unsigned short*)alloc((size_t)N_NODES * 128 * 2);
    unsigned short* z_u  = (unsigned short*)alloc((size_t)N_NODES * 128 * 2);
    unsigned short* cx_n = (unsigned short*)alloc((size_t)N_NODES * 128 * 2);
    unsigned short* cx_u = (unsigned short*)alloc((size_t)N_NODES * 128 * 2);
    (void)in_sizes; (void)n_in; (void)out_size; (void)ws_size;

    (void)hipMemsetAsync(zeros, 0, (size_t)4 * NREP * N_NODES * 4, stream);
    k_prep<<<NB_CONV + NB_W + NB_HIST, 256, 0, stream>>>(
        xu, hu, xn, hn, u3_u, u3_n, Wl, Wr, wt, dun, dnu, deg_n, deg_u);
    k_scan_a<<<dim3(NSB, 2), SCH, 0, stream>>>(deg_n, deg_u, part);
    k_scan_b<<<dim3(NSB, 2), SCH, 0, stream>>>(deg_n, deg_u, part,
                                               offs_n, offs_u, roffs_n, roffs_u);
    k_scatter<<<(2 * NE + 255) / 256, 256, 0, stream>>>(sun, dun, snu, dnu, roffs_n, roffs_u,
                                                        cur_n, cur_u, srcs_n, srcs_u);
    k_agg2<<<dim3(N_NODES / 4, 2), 256, 0, stream>>>(offs_n, srcs_n, offs_u, srcs_u,
                                                     u3_n, u3_u, u3_n, u3_u);
    k_gates<<<dim3((N_NODES + 63) / 64, 2), 512, 64 * GSTRIDE * 2, stream>>>(
        u3_n, u3_u, wt, b, z_n, z_u, cx_n, cx_u, u2s_n, u2s_u);
    k_out<<<dim3((N_NODES + 63) / 64, 2), 512, 64 * OSTRIDE * 2, stream>>>(
        u2s_n, u2s_u, u3_n, u3_u, offs_n, srcs_n, offs_u, srcs_u, wt, b,
        z_n, z_u, cx_n, cx_u, out);
}